// Round 18
// baseline (1744.511 us; speedup 1.0000x reference)
//
#include <hip/hip_runtime.h>
#include <hip/hip_fp16.h>
#include <math.h>

#define M_SLOTS 8192
#define N_DIM   4096
#define FVS     64
#define PLEN    64
#define CDIM    256
#define NIN     512
#define NOUT    512
#define STEPS   8
#define EPS_F   1e-8f

#define RROWS   32                       // rows per read block
#define NRB     (M_SLOTS / RROWS)        // 256 read row-chunks

// ---------------- helpers ----------------

__device__ inline float wave_sum(float v) {
    for (int off = 32; off; off >>= 1) v += __shfl_down(v, off);
    return v;
}

// 256-thread block sum; sh >= 4 floats; all threads get result
__device__ inline float blk_sum_256(float v, float* sh) {
    v = wave_sum(v);
    int lane = threadIdx.x & 63, wid = threadIdx.x >> 6;
    if (lane == 0) sh[wid] = v;
    __syncthreads();
    float r = sh[0] + sh[1] + sh[2] + sh[3];
    __syncthreads();
    return r;
}

// fp16 row load: 4 halves (8B) -> float4
__device__ inline float4 ldh4(const unsigned short* __restrict__ base, size_t idx4) {
    ushort4 u = ((const ushort4*)base)[idx4];
    return make_float4(__half2float(__ushort_as_half(u.x)),
                       __half2float(__ushort_as_half(u.y)),
                       __half2float(__ushort_as_half(u.z)),
                       __half2float(__ushort_as_half(u.w)));
}

// per-row 8 step-weights as two float4 vector loads
template<int NUP>
__device__ inline void ld_ww8(const float* __restrict__ wwT, int m, float wv[8]) {
    const float4* p = (const float4*)(wwT + (size_t)m * 8);
    if (NUP > 0) {
        float4 w0 = p[0];
        wv[0] = w0.x; wv[1] = w0.y; wv[2] = w0.z; wv[3] = w0.w;
    }
    if (NUP > 4) {
        float4 w1 = p[1];
        wv[4] = w1.x; wv[5] = w1.y; wv[6] = w1.z; wv[7] = w1.w;
    }
}

// ---------------- tiny-state kernels ----------------

// one-time: mem0 f32 -> fp16 image.  grid 32768 x 256, thread = 4 elems.
__global__ __launch_bounds__(256) void k_convert(const float* __restrict__ src,
                                                 unsigned short* __restrict__ dst) {
    size_t i = (size_t)blockIdx.x * 256 + threadIdx.x;
    float4 v = ((const float4*)src)[i];
    ushort4 o;
    o.x = __half_as_ushort(__float2half_rn(v.x));
    o.y = __half_as_ushort(__float2half_rn(v.y));
    o.z = __half_as_ushort(__float2half_rn(v.z));
    o.w = __half_as_ushort(__float2half_rn(v.w));
    ((ushort4*)dst)[i] = o;
}

__global__ void k_init_ctrl(const float* __restrict__ x, const float* __restrict__ emb,
                            const float* __restrict__ prog0,
                            const float* __restrict__ Wc, const float* __restrict__ bc,
                            float* __restrict__ X, float* __restrict__ c) {
    __shared__ float in[FVS + PLEN];
    int tid = threadIdx.x;  // 256
    if (tid < FVS) {
        float acc = 0.f;
        for (int i = 0; i < NIN; ++i) acc += x[i] * emb[i * FVS + tid];
        X[tid] = acc;
        in[tid] = acc;
    } else if (tid < FVS + PLEN) {
        in[tid] = prog0[tid - FVS];
    }
    __syncthreads();
    float acc = bc[tid];
    const float* wrow = Wc + tid * (FVS + PLEN);
    #pragma unroll 8
    for (int i = 0; i < FVS + PLEN; ++i) acc += wrow[i] * in[i];
    c[tid] = 1.f / (1.f + expf(-acc));
}

// one wave -> one key row; writes k, e, a, kr plus fused ekr=e*kr, ea=e*a, e2=e*e
__device__ inline void keys_row(int gw, float4 cv, int lane, const float* __restrict__ prog,
                                const float* __restrict__ Wk, const float* __restrict__ bk,
                                const float* __restrict__ We, const float* __restrict__ be,
                                const float* __restrict__ Wa, const float* __restrict__ ba,
                                const float* __restrict__ Wrk, const float* __restrict__ brk,
                                float* __restrict__ k, float* __restrict__ e,
                                float* __restrict__ a, float* __restrict__ kr,
                                float* __restrict__ ekr, float* __restrict__ ea,
                                float* __restrict__ e2) {
    float4 wv;
    wv = ((const float4*)(Wk + (size_t)gw * CDIM))[lane];
    float sK = wv.x*cv.x + wv.y*cv.y + wv.z*cv.z + wv.w*cv.w;
    wv = ((const float4*)(We + (size_t)gw * CDIM))[lane];
    float sE = wv.x*cv.x + wv.y*cv.y + wv.z*cv.z + wv.w*cv.w;
    wv = ((const float4*)(Wa + (size_t)gw * CDIM))[lane];
    float sA = wv.x*cv.x + wv.y*cv.y + wv.z*cv.z + wv.w*cv.w;
    float sR = Wrk[(size_t)gw * PLEN + lane] * prog[lane];
    sK = wave_sum(sK); sE = wave_sum(sE); sA = wave_sum(sA); sR = wave_sum(sR);
    if (lane == 0) {
        float ev  = 1.f / (1.f + expf(-(sE + be[gw])));
        float av  = tanhf(sA + ba[gw]);
        float krv = tanhf(sR + brk[gw]);
        k[gw]   = tanhf(sK + bk[gw]);
        e[gw]   = ev;
        a[gw]   = av;
        kr[gw]  = krv;
        ekr[gw] = ev * krv;
        ea[gw]  = ev * av;
        e2[gw]  = ev * ev;
    }
}

__global__ __launch_bounds__(256) void k_keys4(
        const float* __restrict__ c, const float* __restrict__ prog,
        const float* __restrict__ Wk, const float* __restrict__ bk,
        const float* __restrict__ We, const float* __restrict__ be,
        const float* __restrict__ Wa, const float* __restrict__ ba,
        const float* __restrict__ Wrk, const float* __restrict__ brk,
        float* __restrict__ k, float* __restrict__ e,
        float* __restrict__ a, float* __restrict__ kr,
        float* __restrict__ ekr, float* __restrict__ ea, float* __restrict__ e2) {
    int lane = threadIdx.x & 63, wid = threadIdx.x >> 6;
    const float4 cv = ((const float4*)c)[lane];
    for (int gw = blockIdx.x * 4 + wid; gw < 4096; gw += 2048)
        keys_row(gw, cv, lane, prog, Wk, bk, We, be, Wa, ba, Wrk, brk,
                 k, e, a, kr, ekr, ea, e2);
}

// ---------------- heavy passes (update-replay over fp16 mem0 image) ----------------

// Stats pass at step t, LANE-PER-ROW: each lane owns one memory row and walks
// 128 columns (wave w's sub-stripe of block's 1024-col stripe), accumulating all
// 8 stats in private registers.  ZERO cross-lane ops; one LDS fold per block.
// Wave reads same col-range of 64 adjacent rows -> 8KB L1-resident working set.
// grid (4, 128) x 512.  stat4[(cc*8+st)*M + m],
// st: 0 v.k 1 v.kr 2 v.ekr 3 v.a 4 v.ea 5 v^2 6 v^2.e 7 v^2.e2
template<int NUP>
__global__ __launch_bounds__(512) void k_stats(
        const unsigned short* __restrict__ mem0h,
        const float* __restrict__ ehist, const float* __restrict__ ahist,
        const float* __restrict__ wwT,
        const float* __restrict__ kc, const float* __restrict__ krc,
        const float* __restrict__ ekrc, const float* __restrict__ eac,
        const float* __restrict__ e2c,
        float* __restrict__ stat4) {
    const int tid  = threadIdx.x;
    const int cc   = blockIdx.x;          // col stripe 0..3 (1024 cols each)
    const int rb   = blockIdx.y;          // row block 0..127 (64 rows each)
    const int lane = tid & 63;
    const int w    = tid >> 6;            // wave 0..7, each 128-col sub-stripe
    const int row  = rb * 64 + lane;

    float wv[8];
    ld_ww8<NUP>(wwT, row, wv);

    const int j0base = cc * 1024 + w * 128;
    const size_t rowbase = (size_t)row * N_DIM;

    float sv[8] = {0.f, 0.f, 0.f, 0.f, 0.f, 0.f, 0.f, 0.f};

    for (int it = 0; it < 32; ++it) {
        const int j0 = j0base + it * 4;
        float4 vv = ldh4(mem0h, (rowbase + j0) >> 2);
        #pragma unroll
        for (int s = 0; s < NUP; ++s) {
            const float4 eh = *(const float4*)(ehist + (size_t)s * N_DIM + j0);
            const float4 ah = *(const float4*)(ahist + (size_t)s * N_DIM + j0);
            const float wc = wv[s];
            vv.x = vv.x * (1.f - wc * eh.x) + wc * ah.x;
            vv.y = vv.y * (1.f - wc * eh.y) + wc * ah.y;
            vv.z = vv.z * (1.f - wc * eh.z) + wc * ah.z;
            vv.w = vv.w * (1.f - wc * eh.w) + wc * ah.w;
        }
        const float4 kk  = *(const float4*)(kc + j0);
        const float4 rr  = *(const float4*)(krc + j0);
        const float4 fkr = *(const float4*)(ekrc + j0);
        const float4 ca  = *(const float4*)(ahist + (size_t)NUP * N_DIM + j0);
        const float4 fea = *(const float4*)(eac + j0);
        const float4 ce  = *(const float4*)(ehist + (size_t)NUP * N_DIM + j0);
        const float4 fe2 = *(const float4*)(e2c + j0);
        #define ACC1(vvc,kc_,rc_,ekr_,ac_,ea_,ec_,e2_) { \
            float _v = vvc; float _v2 = _v * _v; \
            sv[0] += _v * kc_;  sv[1] += _v * rc_;  sv[2] += _v * ekr_; \
            sv[3] += _v * ac_;  sv[4] += _v * ea_;  sv[5] += _v2; \
            sv[6] += _v2 * ec_; sv[7] += _v2 * e2_; }
        ACC1(vv.x, kk.x, rr.x, fkr.x, ca.x, fea.x, ce.x, fe2.x)
        ACC1(vv.y, kk.y, rr.y, fkr.y, ca.y, fea.y, ce.y, fe2.y)
        ACC1(vv.z, kk.z, rr.z, fkr.z, ca.z, fea.z, ce.z, fe2.z)
        ACC1(vv.w, kk.w, rr.w, fkr.w, ca.w, fea.w, ce.w, fe2.w)
        #undef ACC1
    }

    __shared__ float shc[8][64][8];
    #pragma unroll
    for (int st = 0; st < 8; ++st) shc[w][lane][st] = sv[st];
    __syncthreads();
    {
        const int r = tid >> 3, st = tid & 7;   // 512 threads = 64 rows x 8 stats
        float tot = 0.f;
        #pragma unroll
        for (int q = 0; q < 8; ++q) tot += shc[q][r][st];
        stat4[(size_t)(cc * 8 + st) * M_SLOTS + rb * 64 + r] = tot;
    }
}

#define ST4(st, m) (stat4[(size_t)(st) * M_SLOTS + (m)] \
                  + stat4[(size_t)((st) + 8) * M_SLOTS + (m)] \
                  + stat4[(size_t)((st) + 16) * M_SLOTS + (m)] \
                  + stat4[(size_t)((st) + 24) * M_SLOTS + (m)])

// Write-softmax numerators.  grid 16 x 256; each thread 2 m's.
__global__ __launch_bounds__(256) void k_addrA(
        const float* __restrict__ kc, const float* __restrict__ stat4,
        float* __restrict__ exp1, float* __restrict__ n2sav,
        float* __restrict__ psum1) {
    __shared__ float sh4[4];
    const int tid = threadIdx.x, b = blockIdx.x;
    float a0 = 0.f;
    for (int i = tid; i < N_DIM; i += 256) { float kv = kc[i]; a0 += kv * kv; }
    float d0 = blk_sum_256(a0, sh4);
    float knorm = sqrtf(d0);
    float ls = 0.f;
    #pragma unroll
    for (int j = 0; j < 2; ++j) {
        int m = b * 512 + j * 256 + tid;
        float sim = ST4(0, m);
        float n2  = ST4(5, m);
        float v = sim / (sqrtf(n2) * knorm + EPS_F);
        float ex = expf(v);              // cosine in [-1,1]: no overflow
        exp1[m] = ex;
        n2sav[m] = n2;
        ls += ex;
    }
    float tot = blk_sum_256(ls, sh4);
    if (tid == 0) psum1[b] = tot;
}

// Read pass at step t (NHIST prior updates from wwT; update t applied with
// locally-computed w1, which is also written to wwT slot NHIST).
template<int NHIST>
__global__ __launch_bounds__(256) void k_read(
        const unsigned short* __restrict__ mem0h,
        const float* __restrict__ ehist, const float* __restrict__ ahist,
        float* __restrict__ wwT,
        const float* __restrict__ krc,
        const float* __restrict__ exp1, const float* __restrict__ n2sav,
        const float* __restrict__ psum1, const float* __restrict__ stat4,
        float* __restrict__ psum2,
        float* __restrict__ partial) {
    const int tid  = threadIdx.x;
    const int cc   = blockIdx.x;
    const int rb   = blockIdx.y;
    const int col4 = cc * 256 + tid;

    __shared__ float sh4[4];
    __shared__ float w1s[RROWS];
    __shared__ float wrs[RROWS];

    const float* ac = ahist + (size_t)NHIST * N_DIM;
    float a1 = 0.f, a2 = 0.f, a3 = 0.f;
    for (int i = tid; i < N_DIM; i += 256) {
        float rv = krc[i], av = ac[i];
        a1 += rv * rv; a2 += av * rv; a3 += av * av;
    }
    float d1 = blk_sum_256(a1, sh4);
    float d2 = blk_sum_256(a2, sh4);
    float d3 = blk_sum_256(a3, sh4);
    float krnorm = sqrtf(d1);

    float s1 = 0.f;
    #pragma unroll
    for (int i = 0; i < 16; ++i) s1 += psum1[i];
    const float inv1 = 1.f / s1;

    if (tid < RROWS) {
        const int m = rb * RROWS + tid;
        float w1 = exp1[m] * inv1;
        w1s[tid] = w1;
        float skr  = ST4(1, m);
        float sekr = ST4(2, m);
        float sa_  = ST4(3, m);
        float sea_ = ST4(4, m);
        float qe_  = ST4(6, m);
        float qe2_ = ST4(7, m);
        float sim2 = skr - w1 * sekr + w1 * d2;
        float n2n  = n2sav[m] - 2.f*w1*qe_ + w1*w1*qe2_
                   + 2.f*w1*sa_ - 2.f*w1*w1*sea_ + w1*w1*d3;
        float v2 = sim2 / (sqrtf(n2n) * krnorm + EPS_F);
        wrs[tid] = expf(v2);
        if (cc == 0) wwT[(size_t)m * 8 + NHIST] = w1;
    }
    __syncthreads();
    if (cc == 0 && tid == 0) {
        float s = 0.f;
        #pragma unroll
        for (int r = 0; r < RROWS; ++r) s += wrs[r];
        psum2[rb] = s;
    }

    const int HN = (NHIST > 0) ? NHIST : 1;
    float4 eh[HN], ah[HN];
    #pragma unroll
    for (int s = 0; s < NHIST; ++s) {
        eh[s] = ((const float4*)(ehist + (size_t)s * N_DIM))[col4];
        ah[s] = ((const float4*)(ahist + (size_t)s * N_DIM))[col4];
    }
    const float4 ce = ((const float4*)(ehist + (size_t)NHIST * N_DIM))[col4];
    const float4 ca = ((const float4*)(ahist + (size_t)NHIST * N_DIM))[col4];

    float4 acc = make_float4(0.f, 0.f, 0.f, 0.f);
    for (int r = 0; r < RROWS; ++r) {
        const int m = rb * RROWS + r;
        float4 v = ldh4(mem0h, (size_t)m * (N_DIM / 4) + col4);
        float wv[8];
        ld_ww8<NHIST>(wwT, m, wv);
        #pragma unroll
        for (int s = 0; s < NHIST; ++s) {
            const float w = wv[s];
            v.x = v.x * (1.f - w * eh[s].x) + w * ah[s].x;
            v.y = v.y * (1.f - w * eh[s].y) + w * ah[s].y;
            v.z = v.z * (1.f - w * eh[s].z) + w * ah[s].z;
            v.w = v.w * (1.f - w * eh[s].w) + w * ah[s].w;
        }
        {
            const float w1 = w1s[r];
            v.x = v.x * (1.f - w1 * ce.x) + w1 * ca.x;
            v.y = v.y * (1.f - w1 * ce.y) + w1 * ca.y;
            v.z = v.z * (1.f - w1 * ce.z) + w1 * ca.z;
            v.w = v.w * (1.f - w1 * ce.w) + w1 * ca.w;
        }
        const float w2 = wrs[r];
        acc.x += w2 * v.x; acc.y += w2 * v.y; acc.z += w2 * v.z; acc.w += w2 * v.w;
    }
    ((float4*)partial)[(size_t)rb * (N_DIM / 4) + col4] = acc;
}

// red[c] = inv2 * sum over NRB partial rows.  grid 64 x 256.  NRB == 256 == blockDim.
__global__ void k_read_reduce(const float* __restrict__ partial,
                              const float* __restrict__ psum2,
                              float* __restrict__ red) {
    __shared__ float sh4[4];
    __shared__ float gsh[4][64];
    float p = psum2[threadIdx.x];
    float tot = blk_sum_256(p, sh4);
    float inv2 = 1.f / tot;
    int l = threadIdx.x & 63;
    int q = threadIdx.x >> 6;
    int c = blockIdx.x * 64 + l;
    float acc = 0.f;
    #pragma unroll 8
    for (int r = q * (NRB / 4); r < (q + 1) * (NRB / 4); ++r)
        acc += partial[(size_t)r * N_DIM + c];
    gsh[q][l] = acc;
    __syncthreads();
    if (threadIdx.x < 64)
        red[blockIdx.x * 64 + threadIdx.x] = inv2 *
            (gsh[0][threadIdx.x] + gsh[1][threadIdx.x] +
             gsh[2][threadIdx.x] + gsh[3][threadIdx.x]);
}

// X_new = tanh(X_old @ red); c = sigmoid(Wc [X_new, prog_next] + bc); next step's keys.
__global__ __launch_bounds__(256) void k_exec_keys(
        const float* __restrict__ Xold, float* __restrict__ Xnew,
        const float* __restrict__ red, const float* __restrict__ prog_next,
        const float* __restrict__ Wc, const float* __restrict__ bc,
        const float* __restrict__ Wk, const float* __restrict__ bk,
        const float* __restrict__ We, const float* __restrict__ be,
        const float* __restrict__ Wa, const float* __restrict__ ba,
        const float* __restrict__ Wrk, const float* __restrict__ brk,
        float* __restrict__ k, float* __restrict__ e,
        float* __restrict__ a, float* __restrict__ kr,
        float* __restrict__ ekr, float* __restrict__ ea, float* __restrict__ e2) {
    __shared__ float xo[FVS];
    __shared__ float xs[FVS];
    __shared__ float cc[CDIM];
    int tid = threadIdx.x, lane = tid & 63, wid = tid >> 6;
    if (tid < FVS) xo[tid] = Xold[tid];
    __syncthreads();
    if (tid < FVS) {
        float acc = 0.f;
        #pragma unroll
        for (int i = 0; i < FVS; ++i) acc += xo[i] * red[i * FVS + tid];
        float xn = tanhf(acc);
        xs[tid] = xn;
        if (blockIdx.x == 0) Xnew[tid] = xn;
    }
    __syncthreads();
    {
        float acc = bc[tid];
        const float* wrow = Wc + tid * (FVS + PLEN);
        #pragma unroll
        for (int i = 0; i < FVS; ++i) acc += wrow[i] * xs[i];
        #pragma unroll
        for (int i = 0; i < PLEN; ++i) acc += wrow[FVS + i] * prog_next[i];
        cc[tid] = 1.f / (1.f + expf(-acc));
    }
    __syncthreads();
    const float4 cv = ((const float4*)cc)[lane];
    for (int gw = blockIdx.x * 4 + wid; gw < 4096; gw += 2048)
        keys_row(gw, cv, lane, prog_next, Wk, bk, We, be, Wa, ba, Wrk, brk,
                 k, e, a, kr, ekr, ea, e2);
}

// final: X_new = tanh(X_old @ red); out = X_new @ out_emb.  1 block x 256.
__global__ void k_final(const float* __restrict__ Xold, const float* __restrict__ red,
                        const float* __restrict__ out_emb, float* __restrict__ out) {
    __shared__ float xo[FVS];
    __shared__ float xs[FVS];
    int tid = threadIdx.x;
    if (tid < FVS) xo[tid] = Xold[tid];
    __syncthreads();
    if (tid < FVS) {
        float acc = 0.f;
        #pragma unroll
        for (int i = 0; i < FVS; ++i) acc += xo[i] * red[i * FVS + tid];
        xs[tid] = tanhf(acc);
    }
    __syncthreads();
    for (int col = tid; col < NOUT; col += 256) {
        float acc = 0.f;
        #pragma unroll
        for (int i = 0; i < FVS; ++i) acc += xs[i] * out_emb[i * NOUT + col];
        out[col] = acc;
    }
}

// ---------------- launch ----------------

extern "C" void kernel_launch(void* const* d_in, const int* in_sizes, int n_in,
                              void* d_out, int out_size, void* d_ws, size_t ws_size,
                              hipStream_t stream) {
    const float* x        = (const float*)d_in[0];
    const float* program  = (const float*)d_in[1];
    const float* memory0  = (const float*)d_in[2];
    const float* in_emb   = (const float*)d_in[3];
    const float* out_emb  = (const float*)d_in[4];
    const float* Wc       = (const float*)d_in[5];
    const float* bc       = (const float*)d_in[6];
    const float* Wk       = (const float*)d_in[7];
    const float* bk       = (const float*)d_in[8];
    const float* We       = (const float*)d_in[9];
    const float* be       = (const float*)d_in[10];
    const float* Wa       = (const float*)d_in[11];
    const float* ba       = (const float*)d_in[12];
    const float* Wrk      = (const float*)d_in[13];
    const float* brk      = (const float*)d_in[14];
    float* out = (float*)d_out;

    float* ws = (float*)d_ws;
    size_t off = 0;
    unsigned short* mem0h = (unsigned short*)(ws + off);
    off += (size_t)M_SLOTS * N_DIM / 2;            // 64MB fp16 image
    float* ehist   = ws + off; off += (size_t)STEPS * N_DIM;
    float* ahist   = ws + off; off += (size_t)STEPS * N_DIM;
    float* wwT     = ws + off; off += (size_t)M_SLOTS * 8;   // [m][8] transposed ww history
    float* kcur    = ws + off; off += N_DIM;
    float* krcur   = ws + off; off += N_DIM;
    float* ekrcur  = ws + off; off += N_DIM;
    float* eacur   = ws + off; off += N_DIM;
    float* e2cur   = ws + off; off += N_DIM;
    float* stat4   = ws + off; off += (size_t)32 * M_SLOTS;
    float* partial = ws + off; off += (size_t)NRB * N_DIM;
    float* exp1    = ws + off; off += M_SLOTS;
    float* n2sav   = ws + off; off += M_SLOTS;
    float* psum1   = ws + off; off += 16;
    float* psum2   = ws + off; off += NRB;
    float* red     = ws + off; off += N_DIM;
    float* Xb0     = ws + off; off += FVS;
    float* Xb1     = ws + off; off += FVS;
    float* c       = ws + off; off += CDIM;

    k_convert<<<(M_SLOTS * (N_DIM / 4)) / 256, 256, 0, stream>>>(memory0, mem0h);
    k_init_ctrl<<<1, 256, 0, stream>>>(x, in_emb, program, Wc, bc, Xb0, c);
    k_keys4<<<512, 256, 0, stream>>>(c, program, Wk, bk, We, be, Wa, ba, Wrk, brk,
                                     kcur, ehist, ahist, krcur, ekrcur, eacur, e2cur);

    const dim3 sgrid(4, M_SLOTS / 64), rgrid(4, NRB);

    for (int t = 0; t < STEPS; ++t) {
        switch (t) {
            case 0: k_stats<0><<<sgrid, 512, 0, stream>>>(mem0h, ehist, ahist, wwT,
                        kcur, krcur, ekrcur, eacur, e2cur, stat4); break;
            case 1: k_stats<1><<<sgrid, 512, 0, stream>>>(mem0h, ehist, ahist, wwT,
                        kcur, krcur, ekrcur, eacur, e2cur, stat4); break;
            case 2: k_stats<2><<<sgrid, 512, 0, stream>>>(mem0h, ehist, ahist, wwT,
                        kcur, krcur, ekrcur, eacur, e2cur, stat4); break;
            case 3: k_stats<3><<<sgrid, 512, 0, stream>>>(mem0h, ehist, ahist, wwT,
                        kcur, krcur, ekrcur, eacur, e2cur, stat4); break;
            case 4: k_stats<4><<<sgrid, 512, 0, stream>>>(mem0h, ehist, ahist, wwT,
                        kcur, krcur, ekrcur, eacur, e2cur, stat4); break;
            case 5: k_stats<5><<<sgrid, 512, 0, stream>>>(mem0h, ehist, ahist, wwT,
                        kcur, krcur, ekrcur, eacur, e2cur, stat4); break;
            case 6: k_stats<6><<<sgrid, 512, 0, stream>>>(mem0h, ehist, ahist, wwT,
                        kcur, krcur, ekrcur, eacur, e2cur, stat4); break;
            case 7: k_stats<7><<<sgrid, 512, 0, stream>>>(mem0h, ehist, ahist, wwT,
                        kcur, krcur, ekrcur, eacur, e2cur, stat4); break;
        }

        k_addrA<<<16, 256, 0, stream>>>(kcur, stat4, exp1, n2sav, psum1);

        switch (t) {
            case 0: k_read<0><<<rgrid, 256, 0, stream>>>(mem0h, ehist, ahist, wwT,
                        krcur, exp1, n2sav, psum1, stat4, psum2, partial); break;
            case 1: k_read<1><<<rgrid, 256, 0, stream>>>(mem0h, ehist, ahist, wwT,
                        krcur, exp1, n2sav, psum1, stat4, psum2, partial); break;
            case 2: k_read<2><<<rgrid, 256, 0, stream>>>(mem0h, ehist, ahist, wwT,
                        krcur, exp1, n2sav, psum1, stat4, psum2, partial); break;
            case 3: k_read<3><<<rgrid, 256, 0, stream>>>(mem0h, ehist, ahist, wwT,
                        krcur, exp1, n2sav, psum1, stat4, psum2, partial); break;
            case 4: k_read<4><<<rgrid, 256, 0, stream>>>(mem0h, ehist, ahist, wwT,
                        krcur, exp1, n2sav, psum1, stat4, psum2, partial); break;
            case 5: k_read<5><<<rgrid, 256, 0, stream>>>(mem0h, ehist, ahist, wwT,
                        krcur, exp1, n2sav, psum1, stat4, psum2, partial); break;
            case 6: k_read<6><<<rgrid, 256, 0, stream>>>(mem0h, ehist, ahist, wwT,
                        krcur, exp1, n2sav, psum1, stat4, psum2, partial); break;
            case 7: k_read<7><<<rgrid, 256, 0, stream>>>(mem0h, ehist, ahist, wwT,
                        krcur, exp1, n2sav, psum1, stat4, psum2, partial); break;
        }

        k_read_reduce<<<64, 256, 0, stream>>>(partial, psum2, red);

        const float* Xcur = (t & 1) ? Xb1 : Xb0;
        float*       Xnxt = (t & 1) ? Xb0 : Xb1;
        if (t < STEPS - 1) {
            k_exec_keys<<<512, 256, 0, stream>>>(
                Xcur, Xnxt, red, program + (t + 1) * PLEN,
                Wc, bc, Wk, bk, We, be, Wa, ba, Wrk, brk,
                kcur, ehist + (size_t)(t + 1) * N_DIM,
                ahist + (size_t)(t + 1) * N_DIM, krcur, ekrcur, eacur, e2cur);
        } else {
            k_final<<<1, 256, 0, stream>>>(Xcur, red, out_emb, out);
        }
    }
}

// Round 19
// 685.890 us; speedup vs baseline: 2.5434x; 2.5434x over previous
//
#include <hip/hip_runtime.h>
#include <hip/hip_fp16.h>
#include <math.h>

#define M_SLOTS 8192
#define N_DIM   4096
#define FVS     64
#define PLEN    64
#define CDIM    256
#define NIN     512
#define NOUT    512
#define STEPS   8
#define EPS_F   1e-8f

#define SROWS   16                       // rows per stats block
#define NSB     (M_SLOTS / SROWS)        // 512 stats row-chunks
#define RROWS   32                       // rows per read block
#define NRB     (M_SLOTS / RROWS)        // 256 read row-chunks

// ---------------- helpers ----------------

__device__ inline float wave_sum(float v) {
    for (int off = 32; off; off >>= 1) v += __shfl_down(v, off);
    return v;
}

// 256-thread block sum; sh >= 4 floats; all threads get result
__device__ inline float blk_sum_256(float v, float* sh) {
    v = wave_sum(v);
    int lane = threadIdx.x & 63, wid = threadIdx.x >> 6;
    if (lane == 0) sh[wid] = v;
    __syncthreads();
    float r = sh[0] + sh[1] + sh[2] + sh[3];
    __syncthreads();
    return r;
}

// DPP cross-lane fetch (VALU pipe, no DS).
template<int CTRL>
__device__ inline float dppf(float x) {
    return __builtin_bit_cast(float, __builtin_amdgcn_update_dpp(
        0, __builtin_bit_cast(int, x), CTRL, 0xF, 0xF, true));
}

// Reduce-scatter within 8-lane groups, pure VALU (DPP).  On return every lane
// holds its group's sum of stat st(lane) = (lane&4) + 2*(lane&1) + ((lane&2)>>1).
__device__ inline float group_reduce8_dpp(const float sv[8], int lane) {
    const bool b2 = (lane & 4) != 0;
    const bool b0 = (lane & 1) != 0;
    const bool b1 = (lane & 2) != 0;
    float a0 = (b2 ? sv[4] : sv[0]) + dppf<0x141>(b2 ? sv[0] : sv[4]);
    float a1 = (b2 ? sv[5] : sv[1]) + dppf<0x141>(b2 ? sv[1] : sv[5]);
    float a2 = (b2 ? sv[6] : sv[2]) + dppf<0x141>(b2 ? sv[2] : sv[6]);
    float a3 = (b2 ? sv[7] : sv[3]) + dppf<0x141>(b2 ? sv[3] : sv[7]);
    float c0 = (b0 ? a2 : a0) + dppf<0xB1>(b0 ? a0 : a2);
    float c1 = (b0 ? a3 : a1) + dppf<0xB1>(b0 ? a1 : a3);
    return (b1 ? c1 : c0) + dppf<0x4E>(b1 ? c0 : c1);
}

// fp16 row load: 4 halves (8B) -> float4
__device__ inline float4 ldh4(const unsigned short* __restrict__ base, size_t idx4) {
    ushort4 u = ((const ushort4*)base)[idx4];
    return make_float4(__half2float(__ushort_as_half(u.x)),
                       __half2float(__ushort_as_half(u.y)),
                       __half2float(__ushort_as_half(u.z)),
                       __half2float(__ushort_as_half(u.w)));
}

// ---------------- tiny-state kernels ----------------

// one-time: mem0 f32 -> fp16 image.  grid 32768 x 256, thread = 4 elems.
__global__ __launch_bounds__(256) void k_convert(const float* __restrict__ src,
                                                 unsigned short* __restrict__ dst) {
    size_t i = (size_t)blockIdx.x * 256 + threadIdx.x;
    float4 v = ((const float4*)src)[i];
    ushort4 o;
    o.x = __half_as_ushort(__float2half_rn(v.x));
    o.y = __half_as_ushort(__float2half_rn(v.y));
    o.z = __half_as_ushort(__float2half_rn(v.z));
    o.w = __half_as_ushort(__float2half_rn(v.w));
    ((ushort4*)dst)[i] = o;
}

__global__ void k_init_ctrl(const float* __restrict__ x, const float* __restrict__ emb,
                            const float* __restrict__ prog0,
                            const float* __restrict__ Wc, const float* __restrict__ bc,
                            float* __restrict__ X, float* __restrict__ c) {
    __shared__ float in[FVS + PLEN];
    int tid = threadIdx.x;  // 256
    if (tid < FVS) {
        float acc = 0.f;
        for (int i = 0; i < NIN; ++i) acc += x[i] * emb[i * FVS + tid];
        X[tid] = acc;
        in[tid] = acc;
    } else if (tid < FVS + PLEN) {
        in[tid] = prog0[tid - FVS];
    }
    __syncthreads();
    float acc = bc[tid];
    const float* wrow = Wc + tid * (FVS + PLEN);
    #pragma unroll 8
    for (int i = 0; i < FVS + PLEN; ++i) acc += wrow[i] * in[i];
    c[tid] = 1.f / (1.f + expf(-acc));
}

// one wave -> one key row; writes k, e, a, kr plus fused ekr=e*kr, ea=e*a, e2=e*e
__device__ inline void keys_row(int gw, float4 cv, int lane, const float* __restrict__ prog,
                                const float* __restrict__ Wk, const float* __restrict__ bk,
                                const float* __restrict__ We, const float* __restrict__ be,
                                const float* __restrict__ Wa, const float* __restrict__ ba,
                                const float* __restrict__ Wrk, const float* __restrict__ brk,
                                float* __restrict__ k, float* __restrict__ e,
                                float* __restrict__ a, float* __restrict__ kr,
                                float* __restrict__ ekr, float* __restrict__ ea,
                                float* __restrict__ e2) {
    float4 wv;
    wv = ((const float4*)(Wk + (size_t)gw * CDIM))[lane];
    float sK = wv.x*cv.x + wv.y*cv.y + wv.z*cv.z + wv.w*cv.w;
    wv = ((const float4*)(We + (size_t)gw * CDIM))[lane];
    float sE = wv.x*cv.x + wv.y*cv.y + wv.z*cv.z + wv.w*cv.w;
    wv = ((const float4*)(Wa + (size_t)gw * CDIM))[lane];
    float sA = wv.x*cv.x + wv.y*cv.y + wv.z*cv.z + wv.w*cv.w;
    float sR = Wrk[(size_t)gw * PLEN + lane] * prog[lane];
    sK = wave_sum(sK); sE = wave_sum(sE); sA = wave_sum(sA); sR = wave_sum(sR);
    if (lane == 0) {
        float ev  = 1.f / (1.f + expf(-(sE + be[gw])));
        float av  = tanhf(sA + ba[gw]);
        float krv = tanhf(sR + brk[gw]);
        k[gw]   = tanhf(sK + bk[gw]);
        e[gw]   = ev;
        a[gw]   = av;
        kr[gw]  = krv;
        ekr[gw] = ev * krv;
        ea[gw]  = ev * av;
        e2[gw]  = ev * ev;
    }
}

__global__ __launch_bounds__(256) void k_keys4(
        const float* __restrict__ c, const float* __restrict__ prog,
        const float* __restrict__ Wk, const float* __restrict__ bk,
        const float* __restrict__ We, const float* __restrict__ be,
        const float* __restrict__ Wa, const float* __restrict__ ba,
        const float* __restrict__ Wrk, const float* __restrict__ brk,
        float* __restrict__ k, float* __restrict__ e,
        float* __restrict__ a, float* __restrict__ kr,
        float* __restrict__ ekr, float* __restrict__ ea, float* __restrict__ e2) {
    int lane = threadIdx.x & 63, wid = threadIdx.x >> 6;
    const float4 cv = ((const float4*)c)[lane];
    for (int gw = blockIdx.x * 4 + wid; gw < 4096; gw += 2048)
        keys_row(gw, cv, lane, prog, Wk, bk, We, be, Wa, ba, Wrk, brk,
                 k, e, a, kr, ekr, ea, e2);
}

// ---------------- heavy passes (update-replay over fp16 mem0 image) ----------------

// Stats pass at step t (NUP prior updates replayed in registers).
// grid (4, NSB) x 256.  stat4[(cc*8+st)*M + m],
// st: 0 v.k 1 v.kr 2 v.ekr 3 v.a 4 v.ea 5 v^2 6 v^2.e 7 v^2.e2
template<int NUP>
__global__ __launch_bounds__(256) void k_stats(
        const unsigned short* __restrict__ mem0h,
        const float* __restrict__ ehist, const float* __restrict__ ahist,
        const float* __restrict__ wwhist,
        const float* __restrict__ kc, const float* __restrict__ krc,
        const float* __restrict__ ekrc, const float* __restrict__ eac,
        const float* __restrict__ e2c,
        float* __restrict__ stat4) {
    const int tid  = threadIdx.x;
    const int cc   = blockIdx.x;
    const int rb   = blockIdx.y;
    const int col4 = cc * 256 + tid;
    const int lane = tid & 63, wid = tid >> 6;
    const int HN   = (NUP > 0) ? NUP : 1;
    float4 eh[HN], ah[HN];
    #pragma unroll
    for (int s = 0; s < NUP; ++s) {
        eh[s] = ((const float4*)(ehist + (size_t)s * N_DIM))[col4];
        ah[s] = ((const float4*)(ahist + (size_t)s * N_DIM))[col4];
    }
    const float4 kk  = ((const float4*)kc)[col4];
    const float4 rr  = ((const float4*)krc)[col4];
    const float4 fkr = ((const float4*)ekrc)[col4];
    const float4 fea = ((const float4*)eac)[col4];
    const float4 fe2 = ((const float4*)e2c)[col4];
    const float4 ce  = ((const float4*)(ehist + (size_t)NUP * N_DIM))[col4];
    const float4 ca  = ((const float4*)(ahist + (size_t)NUP * N_DIM))[col4];

    __shared__ float shc[4][SROWS][64];

    const int stl = (lane & 4) + 2 * (lane & 1) + ((lane & 2) >> 1);

    #pragma unroll
    for (int r = 0; r < SROWS; ++r) {
        const int m = rb * SROWS + r;
        float4 v = ldh4(mem0h, (size_t)m * (N_DIM / 4) + col4);
        #pragma unroll
        for (int s = 0; s < NUP; ++s) {
            float w = wwhist[(size_t)s * M_SLOTS + m];
            v.x = v.x * (1.f - w * eh[s].x) + w * ah[s].x;
            v.y = v.y * (1.f - w * eh[s].y) + w * ah[s].y;
            v.z = v.z * (1.f - w * eh[s].z) + w * ah[s].z;
            v.w = v.w * (1.f - w * eh[s].w) + w * ah[s].w;
        }
        float sv[8] = {0.f, 0.f, 0.f, 0.f, 0.f, 0.f, 0.f, 0.f};
        #define ACC1(vv,kc_,rc_,ekr_,ac_,ea_,ec_,e2_) { \
            float _v = vv; float _v2 = _v * _v; \
            sv[0] += _v * kc_;  sv[1] += _v * rc_;  sv[2] += _v * ekr_; \
            sv[3] += _v * ac_;  sv[4] += _v * ea_;  sv[5] += _v * _v; \
            sv[6] += _v2 * ec_; sv[7] += _v2 * e2_; }
        ACC1(v.x, kk.x, rr.x, fkr.x, ca.x, fea.x, ce.x, fe2.x)
        ACC1(v.y, kk.y, rr.y, fkr.y, ca.y, fea.y, ce.y, fe2.y)
        ACC1(v.z, kk.z, rr.z, fkr.z, ca.z, fea.z, ce.z, fe2.z)
        ACC1(v.w, kk.w, rr.w, fkr.w, ca.w, fea.w, ce.w, fe2.w)
        #undef ACC1
        float g = group_reduce8_dpp(sv, lane);
        shc[wid][r][(lane & 56) + stl] = g;
    }
    __syncthreads();
    if (tid < SROWS * 8) {
        const int r = tid >> 3, st = tid & 7;
        float tot = 0.f;
        #pragma unroll
        for (int w = 0; w < 4; ++w)
            #pragma unroll
            for (int g2 = 0; g2 < 8; ++g2)
                tot += shc[w][r][g2 * 8 + st];
        stat4[(size_t)(cc * 8 + st) * M_SLOTS + rb * SROWS + r] = tot;
    }
}

#define ST4(st, m) (stat4[(size_t)(st) * M_SLOTS + (m)] \
                  + stat4[(size_t)((st) + 8) * M_SLOTS + (m)] \
                  + stat4[(size_t)((st) + 16) * M_SLOTS + (m)] \
                  + stat4[(size_t)((st) + 24) * M_SLOTS + (m)])

// Write-softmax numerators.  grid 16 x 256; each thread 2 m's.
__global__ __launch_bounds__(256) void k_addrA(
        const float* __restrict__ kc, const float* __restrict__ stat4,
        float* __restrict__ exp1, float* __restrict__ n2sav,
        float* __restrict__ psum1) {
    __shared__ float sh4[4];
    const int tid = threadIdx.x, b = blockIdx.x;
    float a0 = 0.f;
    for (int i = tid; i < N_DIM; i += 256) { float kv = kc[i]; a0 += kv * kv; }
    float d0 = blk_sum_256(a0, sh4);
    float knorm = sqrtf(d0);
    float ls = 0.f;
    #pragma unroll
    for (int j = 0; j < 2; ++j) {
        int m = b * 512 + j * 256 + tid;
        float sim = ST4(0, m);
        float n2  = ST4(5, m);
        float v = sim / (sqrtf(n2) * knorm + EPS_F);
        float ex = expf(v);              // cosine in [-1,1]: no overflow
        exp1[m] = ex;
        n2sav[m] = n2;
        ls += ex;
    }
    float tot = blk_sum_256(ls, sh4);
    if (tid == 0) psum1[b] = tot;
}

// Read pass at step t (NHIST prior updates from history; update t applied with
// locally-computed w1).  Prologue finishes both softmaxes for this block's rows.
template<int NHIST>
__global__ __launch_bounds__(256) void k_read(
        const unsigned short* __restrict__ mem0h,
        const float* __restrict__ ehist, const float* __restrict__ ahist,
        const float* __restrict__ wwhist,
        const float* __restrict__ krc,
        const float* __restrict__ exp1, const float* __restrict__ n2sav,
        const float* __restrict__ psum1, const float* __restrict__ stat4,
        float* __restrict__ ww, float* __restrict__ psum2,
        float* __restrict__ partial) {
    const int tid  = threadIdx.x;
    const int cc   = blockIdx.x;
    const int rb   = blockIdx.y;
    const int col4 = cc * 256 + tid;

    __shared__ float sh4[4];
    __shared__ float w1s[RROWS];
    __shared__ float wrs[RROWS];

    const float* ac = ahist + (size_t)NHIST * N_DIM;
    float a1 = 0.f, a2 = 0.f, a3 = 0.f;
    for (int i = tid; i < N_DIM; i += 256) {
        float rv = krc[i], av = ac[i];
        a1 += rv * rv; a2 += av * rv; a3 += av * av;
    }
    float d1 = blk_sum_256(a1, sh4);
    float d2 = blk_sum_256(a2, sh4);
    float d3 = blk_sum_256(a3, sh4);
    float krnorm = sqrtf(d1);

    float s1 = 0.f;
    #pragma unroll
    for (int i = 0; i < 16; ++i) s1 += psum1[i];
    const float inv1 = 1.f / s1;

    if (tid < RROWS) {
        const int m = rb * RROWS + tid;
        float w1 = exp1[m] * inv1;
        w1s[tid] = w1;
        float skr  = ST4(1, m);
        float sekr = ST4(2, m);
        float sa_  = ST4(3, m);
        float sea_ = ST4(4, m);
        float qe_  = ST4(6, m);
        float qe2_ = ST4(7, m);
        float sim2 = skr - w1 * sekr + w1 * d2;
        float n2n  = n2sav[m] - 2.f*w1*qe_ + w1*w1*qe2_
                   + 2.f*w1*sa_ - 2.f*w1*w1*sea_ + w1*w1*d3;
        float v2 = sim2 / (sqrtf(n2n) * krnorm + EPS_F);
        wrs[tid] = expf(v2);
        if (cc == 0) ww[m] = w1;
    }
    __syncthreads();
    if (cc == 0 && tid == 0) {
        float s = 0.f;
        #pragma unroll
        for (int r = 0; r < RROWS; ++r) s += wrs[r];
        psum2[rb] = s;
    }

    const int HN = (NHIST > 0) ? NHIST : 1;
    float4 eh[HN], ah[HN];
    #pragma unroll
    for (int s = 0; s < NHIST; ++s) {
        eh[s] = ((const float4*)(ehist + (size_t)s * N_DIM))[col4];
        ah[s] = ((const float4*)(ahist + (size_t)s * N_DIM))[col4];
    }
    const float4 ce = ((const float4*)(ehist + (size_t)NHIST * N_DIM))[col4];
    const float4 ca = ((const float4*)(ahist + (size_t)NHIST * N_DIM))[col4];

    float4 acc = make_float4(0.f, 0.f, 0.f, 0.f);
    for (int r = 0; r < RROWS; ++r) {
        const int m = rb * RROWS + r;
        float4 v = ldh4(mem0h, (size_t)m * (N_DIM / 4) + col4);
        #pragma unroll
        for (int s = 0; s < NHIST; ++s) {
            float w = wwhist[(size_t)s * M_SLOTS + m];
            v.x = v.x * (1.f - w * eh[s].x) + w * ah[s].x;
            v.y = v.y * (1.f - w * eh[s].y) + w * ah[s].y;
            v.z = v.z * (1.f - w * eh[s].z) + w * ah[s].z;
            v.w = v.w * (1.f - w * eh[s].w) + w * ah[s].w;
        }
        {
            const float w1 = w1s[r];
            v.x = v.x * (1.f - w1 * ce.x) + w1 * ca.x;
            v.y = v.y * (1.f - w1 * ce.y) + w1 * ca.y;
            v.z = v.z * (1.f - w1 * ce.z) + w1 * ca.z;
            v.w = v.w * (1.f - w1 * ce.w) + w1 * ca.w;
        }
        const float w2 = wrs[r];
        acc.x += w2 * v.x; acc.y += w2 * v.y; acc.z += w2 * v.z; acc.w += w2 * v.w;
    }
    ((float4*)partial)[(size_t)rb * (N_DIM / 4) + col4] = acc;
}

// red[c] = inv2 * sum over NRB partial rows.  grid 64 x 256.  NRB == 256 == blockDim.
__global__ void k_read_reduce(const float* __restrict__ partial,
                              const float* __restrict__ psum2,
                              float* __restrict__ red) {
    __shared__ float sh4[4];
    __shared__ float gsh[4][64];
    float p = psum2[threadIdx.x];
    float tot = blk_sum_256(p, sh4);
    float inv2 = 1.f / tot;
    int l = threadIdx.x & 63;
    int q = threadIdx.x >> 6;
    int c = blockIdx.x * 64 + l;
    float acc = 0.f;
    #pragma unroll 8
    for (int r = q * (NRB / 4); r < (q + 1) * (NRB / 4); ++r)
        acc += partial[(size_t)r * N_DIM + c];
    gsh[q][l] = acc;
    __syncthreads();
    if (threadIdx.x < 64)
        red[blockIdx.x * 64 + threadIdx.x] = inv2 *
            (gsh[0][threadIdx.x] + gsh[1][threadIdx.x] +
             gsh[2][threadIdx.x] + gsh[3][threadIdx.x]);
}

// X_new = tanh(X_old @ red); c = sigmoid(Wc [X_new, prog_next] + bc); next step's keys.
__global__ __launch_bounds__(256) void k_exec_keys(
        const float* __restrict__ Xold, float* __restrict__ Xnew,
        const float* __restrict__ red, const float* __restrict__ prog_next,
        const float* __restrict__ Wc, const float* __restrict__ bc,
        const float* __restrict__ Wk, const float* __restrict__ bk,
        const float* __restrict__ We, const float* __restrict__ be,
        const float* __restrict__ Wa, const float* __restrict__ ba,
        const float* __restrict__ Wrk, const float* __restrict__ brk,
        float* __restrict__ k, float* __restrict__ e,
        float* __restrict__ a, float* __restrict__ kr,
        float* __restrict__ ekr, float* __restrict__ ea, float* __restrict__ e2) {
    __shared__ float xo[FVS];
    __shared__ float xs[FVS];
    __shared__ float cc[CDIM];
    int tid = threadIdx.x, lane = tid & 63, wid = tid >> 6;
    if (tid < FVS) xo[tid] = Xold[tid];
    __syncthreads();
    if (tid < FVS) {
        float acc = 0.f;
        #pragma unroll
        for (int i = 0; i < FVS; ++i) acc += xo[i] * red[i * FVS + tid];
        float xn = tanhf(acc);
        xs[tid] = xn;
        if (blockIdx.x == 0) Xnew[tid] = xn;
    }
    __syncthreads();
    {
        float acc = bc[tid];
        const float* wrow = Wc + tid * (FVS + PLEN);
        #pragma unroll
        for (int i = 0; i < FVS; ++i) acc += wrow[i] * xs[i];
        #pragma unroll
        for (int i = 0; i < PLEN; ++i) acc += wrow[FVS + i] * prog_next[i];
        cc[tid] = 1.f / (1.f + expf(-acc));
    }
    __syncthreads();
    const float4 cv = ((const float4*)cc)[lane];
    for (int gw = blockIdx.x * 4 + wid; gw < 4096; gw += 2048)
        keys_row(gw, cv, lane, prog_next, Wk, bk, We, be, Wa, ba, Wrk, brk,
                 k, e, a, kr, ekr, ea, e2);
}

// final: X_new = tanh(X_old @ red); out = X_new @ out_emb.  1 block x 256.
__global__ void k_final(const float* __restrict__ Xold, const float* __restrict__ red,
                        const float* __restrict__ out_emb, float* __restrict__ out) {
    __shared__ float xo[FVS];
    __shared__ float xs[FVS];
    int tid = threadIdx.x;
    if (tid < FVS) xo[tid] = Xold[tid];
    __syncthreads();
    if (tid < FVS) {
        float acc = 0.f;
        #pragma unroll
        for (int i = 0; i < FVS; ++i) acc += xo[i] * red[i * FVS + tid];
        xs[tid] = tanhf(acc);
    }
    __syncthreads();
    for (int col = tid; col < NOUT; col += 256) {
        float acc = 0.f;
        #pragma unroll
        for (int i = 0; i < FVS; ++i) acc += xs[i] * out_emb[i * NOUT + col];
        out[col] = acc;
    }
}

// ---------------- launch ----------------

extern "C" void kernel_launch(void* const* d_in, const int* in_sizes, int n_in,
                              void* d_out, int out_size, void* d_ws, size_t ws_size,
                              hipStream_t stream) {
    const float* x        = (const float*)d_in[0];
    const float* program  = (const float*)d_in[1];
    const float* memory0  = (const float*)d_in[2];
    const float* in_emb   = (const float*)d_in[3];
    const float* out_emb  = (const float*)d_in[4];
    const float* Wc       = (const float*)d_in[5];
    const float* bc       = (const float*)d_in[6];
    const float* Wk       = (const float*)d_in[7];
    const float* bk       = (const float*)d_in[8];
    const float* We       = (const float*)d_in[9];
    const float* be       = (const float*)d_in[10];
    const float* Wa       = (const float*)d_in[11];
    const float* ba       = (const float*)d_in[12];
    const float* Wrk      = (const float*)d_in[13];
    const float* brk      = (const float*)d_in[14];
    float* out = (float*)d_out;

    float* ws = (float*)d_ws;
    size_t off = 0;
    unsigned short* mem0h = (unsigned short*)(ws + off);
    off += (size_t)M_SLOTS * N_DIM / 2;            // 64MB fp16 image
    float* ehist   = ws + off; off += (size_t)STEPS * N_DIM;
    float* ahist   = ws + off; off += (size_t)STEPS * N_DIM;
    float* wwhist  = ws + off; off += (size_t)STEPS * M_SLOTS;
    float* kcur    = ws + off; off += N_DIM;
    float* krcur   = ws + off; off += N_DIM;
    float* ekrcur  = ws + off; off += N_DIM;
    float* eacur   = ws + off; off += N_DIM;
    float* e2cur   = ws + off; off += N_DIM;
    float* stat4   = ws + off; off += (size_t)32 * M_SLOTS;
    float* partial = ws + off; off += (size_t)NRB * N_DIM;
    float* exp1    = ws + off; off += M_SLOTS;
    float* n2sav   = ws + off; off += M_SLOTS;
    float* psum1   = ws + off; off += 16;
    float* psum2   = ws + off; off += NRB;
    float* red     = ws + off; off += N_DIM;
    float* Xb0     = ws + off; off += FVS;
    float* Xb1     = ws + off; off += FVS;
    float* c       = ws + off; off += CDIM;

    k_convert<<<(M_SLOTS * (N_DIM / 4)) / 256, 256, 0, stream>>>(memory0, mem0h);
    k_init_ctrl<<<1, 256, 0, stream>>>(x, in_emb, program, Wc, bc, Xb0, c);
    k_keys4<<<512, 256, 0, stream>>>(c, program, Wk, bk, We, be, Wa, ba, Wrk, brk,
                                     kcur, ehist, ahist, krcur, ekrcur, eacur, e2cur);

    const dim3 sgrid(4, NSB), rgrid(4, NRB);

    for (int t = 0; t < STEPS; ++t) {
        float* wwslot = wwhist + (size_t)t * M_SLOTS;

        switch (t) {
            case 0: k_stats<0><<<sgrid, 256, 0, stream>>>(mem0h, ehist, ahist, wwhist,
                        kcur, krcur, ekrcur, eacur, e2cur, stat4); break;
            case 1: k_stats<1><<<sgrid, 256, 0, stream>>>(mem0h, ehist, ahist, wwhist,
                        kcur, krcur, ekrcur, eacur, e2cur, stat4); break;
            case 2: k_stats<2><<<sgrid, 256, 0, stream>>>(mem0h, ehist, ahist, wwhist,
                        kcur, krcur, ekrcur, eacur, e2cur, stat4); break;
            case 3: k_stats<3><<<sgrid, 256, 0, stream>>>(mem0h, ehist, ahist, wwhist,
                        kcur, krcur, ekrcur, eacur, e2cur, stat4); break;
            case 4: k_stats<4><<<sgrid, 256, 0, stream>>>(mem0h, ehist, ahist, wwhist,
                        kcur, krcur, ekrcur, eacur, e2cur, stat4); break;
            case 5: k_stats<5><<<sgrid, 256, 0, stream>>>(mem0h, ehist, ahist, wwhist,
                        kcur, krcur, ekrcur, eacur, e2cur, stat4); break;
            case 6: k_stats<6><<<sgrid, 256, 0, stream>>>(mem0h, ehist, ahist, wwhist,
                        kcur, krcur, ekrcur, eacur, e2cur, stat4); break;
            case 7: k_stats<7><<<sgrid, 256, 0, stream>>>(mem0h, ehist, ahist, wwhist,
                        kcur, krcur, ekrcur, eacur, e2cur, stat4); break;
        }

        k_addrA<<<16, 256, 0, stream>>>(kcur, stat4, exp1, n2sav, psum1);

        switch (t) {
            case 0: k_read<0><<<rgrid, 256, 0, stream>>>(mem0h, ehist, ahist, wwhist,
                        krcur, exp1, n2sav, psum1, stat4, wwslot, psum2, partial); break;
            case 1: k_read<1><<<rgrid, 256, 0, stream>>>(mem0h, ehist, ahist, wwhist,
                        krcur, exp1, n2sav, psum1, stat4, wwslot, psum2, partial); break;
            case 2: k_read<2><<<rgrid, 256, 0, stream>>>(mem0h, ehist, ahist, wwhist,
                        krcur, exp1, n2sav, psum1, stat4, wwslot, psum2, partial); break;
            case 3: k_read<3><<<rgrid, 256, 0, stream>>>(mem0h, ehist, ahist, wwhist,
                        krcur, exp1, n2sav, psum1, stat4, wwslot, psum2, partial); break;
            case 4: k_read<4><<<rgrid, 256, 0, stream>>>(mem0h, ehist, ahist, wwhist,
                        krcur, exp1, n2sav, psum1, stat4, wwslot, psum2, partial); break;
            case 5: k_read<5><<<rgrid, 256, 0, stream>>>(mem0h, ehist, ahist, wwhist,
                        krcur, exp1, n2sav, psum1, stat4, wwslot, psum2, partial); break;
            case 6: k_read<6><<<rgrid, 256, 0, stream>>>(mem0h, ehist, ahist, wwhist,
                        krcur, exp1, n2sav, psum1, stat4, wwslot, psum2, partial); break;
            case 7: k_read<7><<<rgrid, 256, 0, stream>>>(mem0h, ehist, ahist, wwhist,
                        krcur, exp1, n2sav, psum1, stat4, wwslot, psum2, partial); break;
        }

        k_read_reduce<<<64, 256, 0, stream>>>(partial, psum2, red);

        const float* Xcur = (t & 1) ? Xb1 : Xb0;
        float*       Xnxt = (t & 1) ? Xb0 : Xb1;
        if (t < STEPS - 1) {
            k_exec_keys<<<512, 256, 0, stream>>>(
                Xcur, Xnxt, red, program + (t + 1) * PLEN,
                Wc, bc, Wk, bk, We, be, Wa, ba, Wrk, brk,
                kcur, ehist + (size_t)(t + 1) * N_DIM,
                ahist + (size_t)(t + 1) * N_DIM, krcur, ekrcur, eacur, e2cur);
        } else {
            k_final<<<1, 256, 0, stream>>>(Xcur, red, out_emb, out);
        }
    }
}